// Round 1
// baseline (332.815 us; speedup 1.0000x reference)
//
#include <hip/hip_runtime.h>
#include <hip/hip_bf16.h>

#define BB 32768
#define NN 10
#define VV 2000
#define EPSBN 1e-5

// ---------------- K0: build T1[v][l][o] = emb[v] . W1[o][16l:16l+16] ----------------
__global__ __launch_bounds__(256) void k_table(const float* __restrict__ emb,
                                               const float* __restrict__ W1,
                                               float* __restrict__ T1) {
  int idx = blockIdx.x * 256 + threadIdx.x;
  if (idx >= VV * 640) return;
  int v = idx / 640;
  int r = idx - v * 640;
  int l = r >> 6;
  int o = r & 63;
  const float* e = emb + v * 16;
  const float* w = W1 + o * 160 + l * 16;
  float s = 0.f;
#pragma unroll
  for (int k = 0; k < 16; ++k) s = fmaf(e[k], w[k], s);
  T1[idx] = s;
}

// ---------------- K1: per-(b,n): h1 -> subtree -> LSTM h ----------------
__global__ __launch_bounds__(256) void k_stage1(const int* __restrict__ tokens,
    const float* __restrict__ T1,
    const float* __restrict__ b1v, const float* __restrict__ W2,
    const float* __restrict__ b2v, const float* __restrict__ w_ih,
    const float* __restrict__ b_ih, const float* __restrict__ b_hh,
    float* __restrict__ hbuf) {
  __shared__ float lds[4][160];   // per-wave: h1 @0..63, sub @64..79, act @96..159
  int tid = threadIdx.x;
  int lane = tid & 63;
  int wid = tid >> 6;
  float* wl = lds[wid];
  int j = lane >> 2, p = lane & 3;
  float w2r[16], wir[16];
#pragma unroll
  for (int k = 0; k < 16; ++k) w2r[k] = W2[j * 64 + p * 16 + k];
#pragma unroll
  for (int k = 0; k < 16; ++k) wir[k] = w_ih[lane * 16 + k];
  float b1l = b1v[lane];
  float b2j = b2v[j];
  float bsum = b_ih[lane] + b_hh[lane];
  int gw = blockIdx.x * 4 + wid;
  const int nwaves = 2048 * 4;    // grid is exactly 2048 blocks -> 40 items/wave
  for (int item = gw; item < BB * NN; item += nwaves) {
    int tok = 0;
    if (lane < 10) tok = tokens[item * 10 + lane];
    float h1 = b1l;
#pragma unroll
    for (int l = 0; l < 10; ++l) {
      int t = __builtin_amdgcn_readlane(tok, l);
      h1 += T1[t * 640 + l * 64 + lane];
    }
    h1 = fmaxf(h1, 0.f);
    wl[lane] = h1;
    __syncthreads();
    float part = 0.f;
#pragma unroll
    for (int k = 0; k < 16; k += 4) {
      float4 hv = *(const float4*)&wl[p * 16 + k];
      part = fmaf(w2r[k],     hv.x, part);
      part = fmaf(w2r[k + 1], hv.y, part);
      part = fmaf(w2r[k + 2], hv.z, part);
      part = fmaf(w2r[k + 3], hv.w, part);
    }
    part += __shfl_xor(part, 1);
    part += __shfl_xor(part, 2);
    if (p == 0) wl[64 + j] = part + b2j;
    __syncthreads();
    float g = bsum;
#pragma unroll
    for (int k = 0; k < 16; k += 4) {
      float4 sv = *(const float4*)&wl[64 + k];
      g = fmaf(wir[k],     sv.x, g);
      g = fmaf(wir[k + 1], sv.y, g);
      g = fmaf(wir[k + 2], sv.z, g);
      g = fmaf(wir[k + 3], sv.w, g);
    }
    float act;
    if (lane >= 32 && lane < 48) act = tanhf(g);
    else                         act = 1.f / (1.f + __expf(-g));
    wl[96 + lane] = act;
    __syncthreads();
    if (lane < 16) {
      float ia = act;                 // sigmoid(i_lane), own value
      float ga = wl[96 + 32 + lane];  // tanh(g)
      float oa = wl[96 + 48 + lane];  // sigmoid(o)
      float c = ia * ga;
      hbuf[item * 16 + lane] = oa * tanhf(c);
    }
    __syncthreads();
  }
}

// ---------------- K2: per-tree: child_ff(h160) -> heads + s + M partials ----------------
__global__ __launch_bounds__(256) void k_stage2(const float* __restrict__ hbuf,
    const float* __restrict__ W1, const float* __restrict__ b1v,
    const float* __restrict__ W2, const float* __restrict__ b2v,
    const float* __restrict__ fmW, const float* __restrict__ fmb,
    const float* __restrict__ tsW, const float* __restrict__ tsb,
    const float* __restrict__ suW, const float* __restrict__ sub_b,
    float* __restrict__ out, float* __restrict__ partials) {
  __shared__ float h1b_lds[32 * 68];
  __shared__ float code_lds[32 * 20];
  __shared__ float ff_lds[32 * 12];
  int tid = threadIdx.x;
  int lane = tid & 63;
  int wid = __builtin_amdgcn_readfirstlane(tid >> 6);
  int treeBase = blockIdx.x * 32;
  {   // GEMM: wave computes 8 trees, lane = output o
    int tw = treeBase + wid * 8;
    float acc[8];
#pragma unroll
    for (int t = 0; t < 8; ++t) acc[t] = b1v[lane];
    const float* wrow = W1 + lane * 160;
    const float* xbase = hbuf + (size_t)tw * 160;
    for (int k = 0; k < 160; k += 4) {
      float4 wv = *(const float4*)(wrow + k);
#pragma unroll
      for (int t = 0; t < 8; ++t) {
        float4 xv = *(const float4*)(xbase + t * 160 + k);  // wave-uniform -> s_load
        acc[t] = fmaf(wv.x, xv.x, acc[t]);
        acc[t] = fmaf(wv.y, xv.y, acc[t]);
        acc[t] = fmaf(wv.z, xv.z, acc[t]);
        acc[t] = fmaf(wv.w, xv.w, acc[t]);
      }
    }
#pragma unroll
    for (int t = 0; t < 8; ++t)
      h1b_lds[(wid * 8 + t) * 68 + lane] = fmaxf(acc[t], 0.f);
  }
  __syncthreads();
  {   // code = W2 @ relu(h1b) + b2 : thread -> (tree t2, outputs jj, jj+8)
    int t2 = tid >> 3, jj = tid & 7;
    float c0 = b2v[jj], c1 = b2v[jj + 8];
    const float* w2a = W2 + jj * 64;
    const float* w2b = W2 + (jj + 8) * 64;
    const float* hb = &h1b_lds[t2 * 68];
    for (int o = 0; o < 64; o += 4) {
      float4 hv = *(const float4*)(hb + o);
      float4 a4 = *(const float4*)(w2a + o);
      float4 b4 = *(const float4*)(w2b + o);
      c0 = fmaf(a4.x, hv.x, c0); c0 = fmaf(a4.y, hv.y, c0);
      c0 = fmaf(a4.z, hv.z, c0); c0 = fmaf(a4.w, hv.w, c0);
      c1 = fmaf(b4.x, hv.x, c1); c1 = fmaf(b4.y, hv.y, c1);
      c1 = fmaf(b4.z, hv.z, c1); c1 = fmaf(b4.w, hv.w, c1);
    }
    code_lds[t2 * 20 + jj] = c0;
    code_lds[t2 * 20 + jj + 8] = c1;
  }
  __syncthreads();
  {   // ff_out = fmW @ code + fmb
    int t = tid >> 3, q = tid & 7;
    float f = fmb[q];
    const float* cw = fmW + q * 16;
    const float* cl = &code_lds[t * 20];
#pragma unroll
    for (int j4 = 0; j4 < 16; j4 += 4) {
      float4 cv = *(const float4*)(cl + j4);
      float4 wv = *(const float4*)(cw + j4);
      f = fmaf(wv.x, cv.x, f); f = fmaf(wv.y, cv.y, f);
      f = fmaf(wv.z, cv.z, f); f = fmaf(wv.w, cv.w, f);
    }
    ff_lds[t * 12 + q] = f;
  }
  __syncthreads();
  {   // s (unnormalized) to d_out; score for tid<32
    int t = tid >> 3, r = tid & 7;
    float4 f0 = *(const float4*)&ff_lds[t * 12];
    float4 f1 = *(const float4*)&ff_lds[t * 12 + 4];
    int tree = treeBase + t;
    float* od = out + (size_t)BB + (size_t)tree * 128 + r * 16;
#pragma unroll
    for (int cc = 0; cc < 16; ++cc) {
      int c = r * 16 + cc;
      const float* u = suW + c * 8;
      float4 u0 = *(const float4*)(u);
      float4 u1 = *(const float4*)(u + 4);
      float sv = sub_b[c];
      sv = fmaf(u0.x, f0.x, sv); sv = fmaf(u0.y, f0.y, sv);
      sv = fmaf(u0.z, f0.z, sv); sv = fmaf(u0.w, f0.w, sv);
      sv = fmaf(u1.x, f1.x, sv); sv = fmaf(u1.y, f1.y, sv);
      sv = fmaf(u1.z, f1.z, sv); sv = fmaf(u1.w, f1.w, sv);
      od[cc] = sv;
    }
    if (tid < 32) {
      int tt = tid;
      float4 g0 = *(const float4*)&ff_lds[tt * 12];
      float4 g1 = *(const float4*)&ff_lds[tt * 12 + 4];
      float sc = tsb[0];
      sc = fmaf(tsW[0], g0.x, sc); sc = fmaf(tsW[1], g0.y, sc);
      sc = fmaf(tsW[2], g0.z, sc); sc = fmaf(tsW[3], g0.w, sc);
      sc = fmaf(tsW[4], g1.x, sc); sc = fmaf(tsW[5], g1.y, sc);
      sc = fmaf(tsW[6], g1.z, sc); sc = fmaf(tsW[7], g1.w, sc);
      out[treeBase + tt] = tanhf(sc);
    }
  }
  {   // per-wave 9x9 second-moment partials over its 8 trees (f9 = [ff_out, 1])
    int waveId = blockIdx.x * 4 + wid;
    float* pw = partials + (size_t)waveId * 88;
#pragma unroll
    for (int rep = 0; rep < 2; ++rep) {
      int e = lane + rep * 64;
      if (e < 81) {
        int i = e / 9, jx = e - i * 9;
        float m = 0.f;
#pragma unroll
        for (int t = 0; t < 8; ++t) {
          const float* fr = &ff_lds[(wid * 8 + t) * 12];
          float fi = (i  < 8) ? fr[i]  : 1.f;
          float fj = (jx < 8) ? fr[jx] : 1.f;
          m = fmaf(fi, fj, m);
        }
        pw[e] = m;
      }
    }
  }
}

// ---------------- K3a: reduce M partials (4096 waves) in f64 ----------------
__global__ __launch_bounds__(256) void k_reduce(const float* __restrict__ partials,
                                                double* __restrict__ Msum) {
  __shared__ double red[256];
  int e = blockIdx.x;    // 0..80
  double s = 0.0;
  for (int w = threadIdx.x; w < 4096; w += 256)
    s += (double)partials[(size_t)w * 88 + e];
  red[threadIdx.x] = s;
  __syncthreads();
  for (int off = 128; off > 0; off >>= 1) {
    if (threadIdx.x < off) red[threadIdx.x] += red[threadIdx.x + off];
    __syncthreads();
  }
  if (threadIdx.x == 0) Msum[e] = red[0];
}

// ---------------- K3b: per-column BN stats -> A[c], B[c] ----------------
__global__ __launch_bounds__(128) void k_stats(const double* __restrict__ Msum,
    const float* __restrict__ suW, const float* __restrict__ sub_b,
    const float* __restrict__ gamma, const float* __restrict__ beta,
    float* __restrict__ statsA, float* __restrict__ statsB) {
  int c = threadIdx.x;
  double u[9];
#pragma unroll
  for (int q = 0; q < 8; ++q) u[q] = (double)suW[c * 8 + q];
  u[8] = (double)sub_b[c];
  double S1 = 0.0;
#pragma unroll
  for (int i = 0; i < 9; ++i) S1 += u[i] * Msum[72 + i];   // row 8 of M = sums of f9
  double mu = S1 / (double)BB;
  double E2 = 0.0;
#pragma unroll
  for (int i = 0; i < 9; ++i) {
    double acc = 0.0;
#pragma unroll
    for (int jx = 0; jx < 9; ++jx) acc += u[jx] * Msum[i * 9 + jx];
    E2 += u[i] * acc;
  }
  E2 /= (double)BB;
  double var = E2 - mu * mu;
  if (var < 0.0) var = 0.0;
  double rs = 1.0 / sqrt(var + (double)EPSBN);
  double A = (double)gamma[c] * rs;
  statsA[c] = (float)A;
  statsB[c] = (float)((double)beta[c] - mu * A);
}

// ---------------- K4: in-place normalize summary region of d_out ----------------
__global__ __launch_bounds__(256) void k_norm(float* __restrict__ out,
    const float* __restrict__ statsA, const float* __restrict__ statsB) {
  int idx = blockIdx.x * 256 + threadIdx.x;   // 1,048,576 float4s
  float4* p = (float4*)(out + BB);
  float4 v = p[idx];
  int c4 = idx & 31;
  float4 a = ((const float4*)statsA)[c4];
  float4 b = ((const float4*)statsB)[c4];
  v.x = fmaf(v.x, a.x, b.x);
  v.y = fmaf(v.y, a.y, b.y);
  v.z = fmaf(v.z, a.z, b.z);
  v.w = fmaf(v.w, a.w, b.w);
  p[idx] = v;
}

extern "C" void kernel_launch(void* const* d_in, const int* in_sizes, int n_in,
                              void* d_out, int out_size, void* d_ws, size_t ws_size,
                              hipStream_t stream) {
  const int*   tokens = (const int*)d_in[0];
  const float* emb   = (const float*)d_in[1];
  const float* w_ih  = (const float*)d_in[2];
  const float* b_ih  = (const float*)d_in[3];
  const float* b_hh  = (const float*)d_in[4];
  const float* ffW1  = (const float*)d_in[5];
  const float* ffb1  = (const float*)d_in[6];
  const float* ffW2  = (const float*)d_in[7];
  const float* ffb2  = (const float*)d_in[8];
  const float* fmW   = (const float*)d_in[9];
  const float* fmb   = (const float*)d_in[10];
  const float* tsW   = (const float*)d_in[11];
  const float* tsb   = (const float*)d_in[12];
  const float* suW   = (const float*)d_in[13];
  const float* sub_b = (const float*)d_in[14];
  const float* gamma = (const float*)d_in[15];
  const float* beta  = (const float*)d_in[16];
  float* out = (float*)d_out;
  float* ws = (float*)d_ws;

  float*  T1       = ws;                               // 1,280,000 f
  float*  hbuf     = T1 + 1280000;                     // 5,242,880 f
  float*  partials = hbuf + 5242880;                   // 360,448 f
  double* Msum     = (double*)(partials + 360448);     // 81 d (8B aligned)
  float*  statsA   = (float*)(Msum + 82);              // 128 f (16B aligned)
  float*  statsB   = statsA + 128;                     // 128 f

  hipLaunchKernelGGL(k_table,  dim3(5000), dim3(256), 0, stream, emb, ffW1, T1);
  hipLaunchKernelGGL(k_stage1, dim3(2048), dim3(256), 0, stream,
                     tokens, T1, ffb1, ffW2, ffb2, w_ih, b_ih, b_hh, hbuf);
  hipLaunchKernelGGL(k_stage2, dim3(1024), dim3(256), 0, stream,
                     hbuf, ffW1, ffb1, ffW2, ffb2, fmW, fmb, tsW, tsb, suW, sub_b,
                     out, partials);
  hipLaunchKernelGGL(k_reduce, dim3(81),   dim3(256), 0, stream, partials, Msum);
  hipLaunchKernelGGL(k_stats,  dim3(1),    dim3(128), 0, stream,
                     Msum, suW, sub_b, gamma, beta, statsA, statsB);
  hipLaunchKernelGGL(k_norm,   dim3(4096), dim3(256), 0, stream, out, statsA, statsB);
}

// Round 2
// 195.500 us; speedup vs baseline: 1.7024x; 1.7024x over previous
//
#include <hip/hip_runtime.h>
#include <hip/hip_bf16.h>

#define BB 32768
#define NN 10
#define VV 2000
#define EPSBN 1e-5

// ---------------- K0: build T1[v][l][o] = emb[v] . W1[o][16l:16l+16] ----------------
__global__ __launch_bounds__(256) void k_table(const float* __restrict__ emb,
                                               const float* __restrict__ W1,
                                               float* __restrict__ T1) {
  int idx = blockIdx.x * 256 + threadIdx.x;
  if (idx >= VV * 640) return;
  int v = idx / 640;
  int r = idx - v * 640;
  int l = r >> 6;
  int o = r & 63;
  const float* e = emb + v * 16;
  const float* w = W1 + o * 160 + l * 16;
  float s = 0.f;
#pragma unroll
  for (int k = 0; k < 16; ++k) s = fmaf(e[k], w[k], s);
  T1[idx] = s;
}

// ---------------- K0b: fuse W3 = w_ih @ W2, bias3 = w_ih @ b2 + b_ih + b_hh ----------------
__global__ __launch_bounds__(256) void k_fuse(const float* __restrict__ w_ih,
    const float* __restrict__ b_ih, const float* __restrict__ b_hh,
    const float* __restrict__ W2, const float* __restrict__ b2v,
    float* __restrict__ W3, float* __restrict__ bias3) {
  int idx = blockIdx.x * 256 + threadIdx.x;
  if (idx < 4096) {
    int j = idx >> 6, k = idx & 63;
    float s = 0.f;
#pragma unroll
    for (int o = 0; o < 16; ++o) s = fmaf(w_ih[j * 16 + o], W2[o * 64 + k], s);
    W3[idx] = s;
  } else if (idx < 4160) {
    int j = idx - 4096;
    float s = b_ih[j] + b_hh[j];
#pragma unroll
    for (int o = 0; o < 16; ++o) s = fmaf(w_ih[j * 16 + o], b2v[o], s);
    bias3[j] = s;
  }
}

// ---------------- K1: per-(b,n): h1 -> gates = W3@relu(h1)+bias3 -> LSTM h ----------------
// Waves are fully independent (each uses its own 64-float LDS slice); intra-wave
// LDS write->read is in-order in the LDS pipe, so wave_barrier (compile-time
// scheduling fence only, no vmcnt drain) replaces __syncthreads. Gathers for
// item i+1 and the token load for item i+2 are issued before item i's matvec.
__global__ __launch_bounds__(256) void k_stage1(const int* __restrict__ tokens,
    const float* __restrict__ T1, const float* __restrict__ b1v,
    const float* __restrict__ W3, const float* __restrict__ bias3,
    float* __restrict__ hbuf) {
  __shared__ float lds[4][64];
  const int tid = threadIdx.x;
  const int lane = tid & 63;
  const int wid = tid >> 6;
  float* wl = lds[wid];
  float w3r[64];
#pragma unroll
  for (int k = 0; k < 64; k += 4) {
    float4 v = *(const float4*)&W3[lane * 64 + k];
    w3r[k] = v.x; w3r[k + 1] = v.y; w3r[k + 2] = v.z; w3r[k + 3] = v.w;
  }
  const float b1l = b1v[lane];
  const float b3l = bias3[lane];
  const bool isG = ((lane >> 4) == 2);     // lanes 32..47 hold the 'g' gate
  const int gw = blockIdx.x * 4 + wid;     // 8192 waves, 40 items each

  int item = gw;
  // prologue: tokens + gathers for item 0; tokens for item 1
  int tokv = (lane < 10) ? tokens[item * 10 + lane] : 0;
  float t[10];
#pragma unroll
  for (int l = 0; l < 10; ++l) {
    int tv = __builtin_amdgcn_readlane(tokv, l);
    t[l] = T1[tv * 640 + l * 64 + lane];
  }
  tokv = (lane < 10) ? tokens[(item + 8192) * 10 + lane] : 0;

  for (int iter = 0; iter < 40; ++iter) {
    // h1 for current item (waits on gathers issued last iteration)
    float h1 = b1l;
#pragma unroll
    for (int l = 0; l < 10; ++l) h1 += t[l];
    h1 = fmaxf(h1, 0.f);
    wl[lane] = h1;
    __builtin_amdgcn_wave_barrier();

    // issue next item's gathers + next-next token load (hide under matvec)
    {
      int tok_n = tokv;
      int nxt2 = item + 16384;
      int src = (nxt2 < BB * NN) ? nxt2 : item;
      tokv = (lane < 10) ? tokens[src * 10 + lane] : 0;
#pragma unroll
      for (int l = 0; l < 10; ++l) {
        int tv = __builtin_amdgcn_readlane(tok_n, l);
        t[l] = T1[tv * 640 + l * 64 + lane];
      }
    }

    // gates = W3 @ h1 + bias3 (broadcast LDS reads, conflict-free)
    float g = b3l;
#pragma unroll
    for (int k = 0; k < 64; k += 4) {
      float4 hv = *(const float4*)&wl[k];
      g = fmaf(w3r[k],     hv.x, g);
      g = fmaf(w3r[k + 1], hv.y, g);
      g = fmaf(w3r[k + 2], hv.z, g);
      g = fmaf(w3r[k + 3], hv.w, g);
    }

    // activation: sigmoid for i,f,o lanes; tanh for g lanes
    float e = __expf(isG ? -2.f * g : -g);
    float r = 1.f / (1.f + e);
    float act = isG ? fmaf(2.f, r, -1.f) : r;

    // h = sigmoid(o) * tanh(sigmoid(i)*tanh(g)), lanes 0..15 store
    int sl = lane & 15;
    float ga = __shfl(act, sl + 32);
    float oa = __shfl(act, sl + 48);
    if (lane < 16) {
      float c = act * ga;
      float e2 = __expf(-2.f * c);
      float th = fmaf(2.f, 1.f / (1.f + e2), -1.f);
      hbuf[item * 16 + lane] = oa * th;
    }
    __builtin_amdgcn_wave_barrier();
    item += 8192;
  }
}

// ---------------- K2: per-tree: child_ff(h160) -> heads + s + M partials ----------------
__global__ __launch_bounds__(256) void k_stage2(const float* __restrict__ hbuf,
    const float* __restrict__ W1, const float* __restrict__ b1v,
    const float* __restrict__ W2, const float* __restrict__ b2v,
    const float* __restrict__ fmW, const float* __restrict__ fmb,
    const float* __restrict__ tsW, const float* __restrict__ tsb,
    const float* __restrict__ suW, const float* __restrict__ sub_b,
    float* __restrict__ out, float* __restrict__ partials) {
  __shared__ float h1b_lds[32 * 68];
  __shared__ float code_lds[32 * 20];
  __shared__ float ff_lds[32 * 12];
  int tid = threadIdx.x;
  int lane = tid & 63;
  int wid = __builtin_amdgcn_readfirstlane(tid >> 6);
  int treeBase = blockIdx.x * 32;
  {   // GEMM: wave computes 8 trees, lane = output o
    int tw = treeBase + wid * 8;
    float acc[8];
#pragma unroll
    for (int t = 0; t < 8; ++t) acc[t] = b1v[lane];
    const float* wrow = W1 + lane * 160;
    const float* xbase = hbuf + (size_t)tw * 160;
    for (int k = 0; k < 160; k += 4) {
      float4 wv = *(const float4*)(wrow + k);
#pragma unroll
      for (int t = 0; t < 8; ++t) {
        float4 xv = *(const float4*)(xbase + t * 160 + k);  // wave-uniform -> s_load
        acc[t] = fmaf(wv.x, xv.x, acc[t]);
        acc[t] = fmaf(wv.y, xv.y, acc[t]);
        acc[t] = fmaf(wv.z, xv.z, acc[t]);
        acc[t] = fmaf(wv.w, xv.w, acc[t]);
      }
    }
#pragma unroll
    for (int t = 0; t < 8; ++t)
      h1b_lds[(wid * 8 + t) * 68 + lane] = fmaxf(acc[t], 0.f);
  }
  __syncthreads();
  {   // code = W2 @ relu(h1b) + b2 : thread -> (tree t2, outputs jj, jj+8)
    int t2 = tid >> 3, jj = tid & 7;
    float c0 = b2v[jj], c1 = b2v[jj + 8];
    const float* w2a = W2 + jj * 64;
    const float* w2b = W2 + (jj + 8) * 64;
    const float* hb = &h1b_lds[t2 * 68];
    for (int o = 0; o < 64; o += 4) {
      float4 hv = *(const float4*)(hb + o);
      float4 a4 = *(const float4*)(w2a + o);
      float4 b4 = *(const float4*)(w2b + o);
      c0 = fmaf(a4.x, hv.x, c0); c0 = fmaf(a4.y, hv.y, c0);
      c0 = fmaf(a4.z, hv.z, c0); c0 = fmaf(a4.w, hv.w, c0);
      c1 = fmaf(b4.x, hv.x, c1); c1 = fmaf(b4.y, hv.y, c1);
      c1 = fmaf(b4.z, hv.z, c1); c1 = fmaf(b4.w, hv.w, c1);
    }
    code_lds[t2 * 20 + jj] = c0;
    code_lds[t2 * 20 + jj + 8] = c1;
  }
  __syncthreads();
  {   // ff_out = fmW @ code + fmb
    int t = tid >> 3, q = tid & 7;
    float f = fmb[q];
    const float* cw = fmW + q * 16;
    const float* cl = &code_lds[t * 20];
#pragma unroll
    for (int j4 = 0; j4 < 16; j4 += 4) {
      float4 cv = *(const float4*)(cl + j4);
      float4 wv = *(const float4*)(cw + j4);
      f = fmaf(wv.x, cv.x, f); f = fmaf(wv.y, cv.y, f);
      f = fmaf(wv.z, cv.z, f); f = fmaf(wv.w, cv.w, f);
    }
    ff_lds[t * 12 + q] = f;
  }
  __syncthreads();
  {   // s (unnormalized) to d_out; score for tid<32
    int t = tid >> 3, r = tid & 7;
    float4 f0 = *(const float4*)&ff_lds[t * 12];
    float4 f1 = *(const float4*)&ff_lds[t * 12 + 4];
    int tree = treeBase + t;
    float* od = out + (size_t)BB + (size_t)tree * 128 + r * 16;
#pragma unroll
    for (int cc = 0; cc < 16; ++cc) {
      int c = r * 16 + cc;
      const float* u = suW + c * 8;
      float4 u0 = *(const float4*)(u);
      float4 u1 = *(const float4*)(u + 4);
      float sv = sub_b[c];
      sv = fmaf(u0.x, f0.x, sv); sv = fmaf(u0.y, f0.y, sv);
      sv = fmaf(u0.z, f0.z, sv); sv = fmaf(u0.w, f0.w, sv);
      sv = fmaf(u1.x, f1.x, sv); sv = fmaf(u1.y, f1.y, sv);
      sv = fmaf(u1.z, f1.z, sv); sv = fmaf(u1.w, f1.w, sv);
      od[cc] = sv;
    }
    if (tid < 32) {
      int tt = tid;
      float4 g0 = *(const float4*)&ff_lds[tt * 12];
      float4 g1 = *(const float4*)&ff_lds[tt * 12 + 4];
      float sc = tsb[0];
      sc = fmaf(tsW[0], g0.x, sc); sc = fmaf(tsW[1], g0.y, sc);
      sc = fmaf(tsW[2], g0.z, sc); sc = fmaf(tsW[3], g0.w, sc);
      sc = fmaf(tsW[4], g1.x, sc); sc = fmaf(tsW[5], g1.y, sc);
      sc = fmaf(tsW[6], g1.z, sc); sc = fmaf(tsW[7], g1.w, sc);
      out[treeBase + tt] = tanhf(sc);
    }
  }
  {   // per-wave 9x9 second-moment partials over its 8 trees (f9 = [ff_out, 1])
    int waveId = blockIdx.x * 4 + wid;
    float* pw = partials + (size_t)waveId * 88;
#pragma unroll
    for (int rep = 0; rep < 2; ++rep) {
      int e = lane + rep * 64;
      if (e < 81) {
        int i = e / 9, jx = e - i * 9;
        float m = 0.f;
#pragma unroll
        for (int t = 0; t < 8; ++t) {
          const float* fr = &ff_lds[(wid * 8 + t) * 12];
          float fi = (i  < 8) ? fr[i]  : 1.f;
          float fj = (jx < 8) ? fr[jx] : 1.f;
          m = fmaf(fi, fj, m);
        }
        pw[e] = m;
      }
    }
  }
}

// ---------------- K3a: reduce M partials (4096 waves) in f64 ----------------
__global__ __launch_bounds__(256) void k_reduce(const float* __restrict__ partials,
                                                double* __restrict__ Msum) {
  __shared__ double red[256];
  int e = blockIdx.x;    // 0..80
  double s = 0.0;
  for (int w = threadIdx.x; w < 4096; w += 256)
    s += (double)partials[(size_t)w * 88 + e];
  red[threadIdx.x] = s;
  __syncthreads();
  for (int off = 128; off > 0; off >>= 1) {
    if (threadIdx.x < off) red[threadIdx.x] += red[threadIdx.x + off];
    __syncthreads();
  }
  if (threadIdx.x == 0) Msum[e] = red[0];
}

// ---------------- K3b: per-column BN stats -> A[c], B[c] ----------------
__global__ __launch_bounds__(128) void k_stats(const double* __restrict__ Msum,
    const float* __restrict__ suW, const float* __restrict__ sub_b,
    const float* __restrict__ gamma, const float* __restrict__ beta,
    float* __restrict__ statsA, float* __restrict__ statsB) {
  int c = threadIdx.x;
  double u[9];
#pragma unroll
  for (int q = 0; q < 8; ++q) u[q] = (double)suW[c * 8 + q];
  u[8] = (double)sub_b[c];
  double S1 = 0.0;
#pragma unroll
  for (int i = 0; i < 9; ++i) S1 += u[i] * Msum[72 + i];   // row 8 of M = sums of f9
  double mu = S1 / (double)BB;
  double E2 = 0.0;
#pragma unroll
  for (int i = 0; i < 9; ++i) {
    double acc = 0.0;
#pragma unroll
    for (int jx = 0; jx < 9; ++jx) acc += u[jx] * Msum[i * 9 + jx];
    E2 += u[i] * acc;
  }
  E2 /= (double)BB;
  double var = E2 - mu * mu;
  if (var < 0.0) var = 0.0;
  double rs = 1.0 / sqrt(var + (double)EPSBN);
  double A = (double)gamma[c] * rs;
  statsA[c] = (float)A;
  statsB[c] = (float)((double)beta[c] - mu * A);
}

// ---------------- K4: in-place normalize summary region of d_out ----------------
__global__ __launch_bounds__(256) void k_norm(float* __restrict__ out,
    const float* __restrict__ statsA, const float* __restrict__ statsB) {
  int idx = blockIdx.x * 256 + threadIdx.x;   // 1,048,576 float4s
  float4* p = (float4*)(out + BB);
  float4 v = p[idx];
  int c4 = idx & 31;
  float4 a = ((const float4*)statsA)[c4];
  float4 b = ((const float4*)statsB)[c4];
  v.x = fmaf(v.x, a.x, b.x);
  v.y = fmaf(v.y, a.y, b.y);
  v.z = fmaf(v.z, a.z, b.z);
  v.w = fmaf(v.w, a.w, b.w);
  p[idx] = v;
}

extern "C" void kernel_launch(void* const* d_in, const int* in_sizes, int n_in,
                              void* d_out, int out_size, void* d_ws, size_t ws_size,
                              hipStream_t stream) {
  const int*   tokens = (const int*)d_in[0];
  const float* emb   = (const float*)d_in[1];
  const float* w_ih  = (const float*)d_in[2];
  const float* b_ih  = (const float*)d_in[3];
  const float* b_hh  = (const float*)d_in[4];
  const float* ffW1  = (const float*)d_in[5];
  const float* ffb1  = (const float*)d_in[6];
  const float* ffW2  = (const float*)d_in[7];
  const float* ffb2  = (const float*)d_in[8];
  const float* fmW   = (const float*)d_in[9];
  const float* fmb   = (const float*)d_in[10];
  const float* tsW   = (const float*)d_in[11];
  const float* tsb   = (const float*)d_in[12];
  const float* suW   = (const float*)d_in[13];
  const float* sub_b = (const float*)d_in[14];
  const float* gamma = (const float*)d_in[15];
  const float* beta  = (const float*)d_in[16];
  float* out = (float*)d_out;
  float* ws = (float*)d_ws;

  float*  T1       = ws;                               // 1,280,000 f
  float*  hbuf     = T1 + 1280000;                     // 5,242,880 f
  float*  partials = hbuf + 5242880;                   // 360,448 f
  double* Msum     = (double*)(partials + 360448);     // 81 d (8B aligned)
  float*  statsA   = (float*)(Msum + 82);              // 128 f (16B aligned)
  float*  statsB   = statsA + 128;                     // 128 f
  float*  W3       = statsB + 128;                     // 4096 f
  float*  bias3    = W3 + 4096;                        // 64 f

  hipLaunchKernelGGL(k_table,  dim3(5000), dim3(256), 0, stream, emb, ffW1, T1);
  hipLaunchKernelGGL(k_fuse,   dim3(17),   dim3(256), 0, stream,
                     w_ih, b_ih, b_hh, ffW2, ffb2, W3, bias3);
  hipLaunchKernelGGL(k_stage1, dim3(2048), dim3(256), 0, stream,
                     tokens, T1, ffb1, W3, bias3, hbuf);
  hipLaunchKernelGGL(k_stage2, dim3(1024), dim3(256), 0, stream,
                     hbuf, ffW1, ffb1, ffW2, ffb2, fmW, fmb, tsW, tsb, suW, sub_b,
                     out, partials);
  hipLaunchKernelGGL(k_reduce, dim3(81),   dim3(256), 0, stream, partials, Msum);
  hipLaunchKernelGGL(k_stats,  dim3(1),    dim3(128), 0, stream,
                     Msum, suW, sub_b, gamma, beta, statsA, statsB);
  hipLaunchKernelGGL(k_norm,   dim3(4096), dim3(256), 0, stream, out, statsA, statsB);
}

// Round 3
// 186.478 us; speedup vs baseline: 1.7847x; 1.0484x over previous
//
#include <hip/hip_runtime.h>
#include <hip/hip_bf16.h>

#define BB 32768
#define NN 10
#define VV 2000
#define EPSBN 1e-5

// ---------------- K0: build T1[v][l][o] = emb[v] . W1[o][16l:16l+16] ----------------
__global__ __launch_bounds__(256) void k_table(const float* __restrict__ emb,
                                               const float* __restrict__ W1,
                                               float* __restrict__ T1) {
  int idx = blockIdx.x * 256 + threadIdx.x;
  if (idx >= VV * 640) return;
  int v = idx / 640;
  int r = idx - v * 640;
  int l = r >> 6;
  int o = r & 63;
  const float* e = emb + v * 16;
  const float* w = W1 + o * 160 + l * 16;
  float s = 0.f;
#pragma unroll
  for (int k = 0; k < 16; ++k) s = fmaf(e[k], w[k], s);
  T1[idx] = s;
}

// ---------------- K0b: fuse W3 = w_ih @ W2, bias3 = w_ih @ b2 + b_ih + b_hh ----------------
__global__ __launch_bounds__(256) void k_fuse(const float* __restrict__ w_ih,
    const float* __restrict__ b_ih, const float* __restrict__ b_hh,
    const float* __restrict__ W2, const float* __restrict__ b2v,
    float* __restrict__ W3, float* __restrict__ bias3) {
  int idx = blockIdx.x * 256 + threadIdx.x;
  if (idx < 4096) {
    int j = idx >> 6, k = idx & 63;
    float s = 0.f;
#pragma unroll
    for (int o = 0; o < 16; ++o) s = fmaf(w_ih[j * 16 + o], W2[o * 64 + k], s);
    W3[idx] = s;
  } else if (idx < 4160) {
    int j = idx - 4096;
    float s = b_ih[j] + b_hh[j];
#pragma unroll
    for (int o = 0; o < 16; ++o) s = fmaf(w_ih[j * 16 + o], b2v[o], s);
    bias3[j] = s;
  }
}

// ---------------- K1: per-(b,n): h1 -> gates = W3@relu(h1)+bias3 -> LSTM h ----------------
// launch_bounds(256,4): VGPR cap 128 so the 64-float W3 row stays register-
// resident (round-2 regression: default cap 64 VGPR -> compiler re-loaded W3
// from global every item). asm pin blocks rematerialization. Tokens read via
// wave-uniform expressions -> s_load (SALU addressing, no readlane). 2-deep
// software pipeline: gathers for item i+2 + tokens for i+4 issued at item i.
#define K1_WAVES 16384
#define K1_ITEMS 20

#define K1_STEP(ITEM, T, TOK, NIDX)                                        \
  {                                                                        \
    float h1 = b1l;                                                        \
    _Pragma("unroll") for (int l = 0; l < 10; ++l) h1 += T[l];             \
    h1 = fmaxf(h1, 0.f);                                                   \
    wl[lane] = h1;                                                         \
    __builtin_amdgcn_wave_barrier();                                       \
    _Pragma("unroll") for (int l = 0; l < 10; ++l) {                       \
      T[l] = T1[TOK[l] * 640 + l * 64 + lane];                             \
    }                                                                      \
    {                                                                      \
      int ci = (NIDX) < BB * NN ? (NIDX) : 0;                              \
      const int* tpn = tokens + (size_t)ci * 10;                           \
      _Pragma("unroll") for (int l = 0; l < 10; ++l) TOK[l] = tpn[l];      \
    }                                                                      \
    float g = b3l;                                                         \
    _Pragma("unroll") for (int k = 0; k < 64; k += 4) {                    \
      float4 hv = *(const float4*)&wl[k];                                  \
      g = fmaf(w3r[k],     hv.x, g);                                       \
      g = fmaf(w3r[k + 1], hv.y, g);                                       \
      g = fmaf(w3r[k + 2], hv.z, g);                                       \
      g = fmaf(w3r[k + 3], hv.w, g);                                       \
    }                                                                      \
    float e = __expf(isG ? -2.f * g : -g);                                 \
    float r = __builtin_amdgcn_rcpf(1.f + e);                              \
    float act = isG ? fmaf(2.f, r, -1.f) : r;                              \
    int sl = lane & 15;                                                    \
    float ga = __shfl(act, sl + 32);                                       \
    float oa = __shfl(act, sl + 48);                                       \
    if (lane < 16) {                                                       \
      float c = act * ga;                                                  \
      float e2 = __expf(-2.f * c);                                         \
      float th = fmaf(2.f, __builtin_amdgcn_rcpf(1.f + e2), -1.f);         \
      hbuf[(size_t)(ITEM) * 16 + lane] = oa * th;                          \
    }                                                                      \
    __builtin_amdgcn_wave_barrier();                                       \
  }

__global__ __launch_bounds__(256, 4) void k_stage1(const int* __restrict__ tokens,
    const float* __restrict__ T1, const float* __restrict__ b1v,
    const float* __restrict__ W3, const float* __restrict__ bias3,
    float* __restrict__ hbuf) {
  __shared__ float lds[4][64];
  const int tid = threadIdx.x;
  const int lane = tid & 63;
  const int wid = __builtin_amdgcn_readfirstlane(tid >> 6);
  float* wl = lds[wid];

  float w3r[64];
#pragma unroll
  for (int k = 0; k < 64; k += 4) {
    float4 v = *(const float4*)&W3[lane * 64 + k];
    w3r[k] = v.x; w3r[k + 1] = v.y; w3r[k + 2] = v.z; w3r[k + 3] = v.w;
  }
#pragma unroll
  for (int k = 0; k < 64; ++k) asm volatile("" : "+v"(w3r[k]));  // pin: no remat

  const float b1l = b1v[lane];
  const float b3l = bias3[lane];
  const bool isG = ((lane >> 4) == 2);   // lanes 32..47 hold the 'g' gate
  const int gw = __builtin_amdgcn_readfirstlane(blockIdx.x * 4 + wid);

  int tokA[10], tokB[10];
  float tA[10], tB[10];
  {  // tokens for items 0,1 (wave-uniform -> s_load)
    const int* t0 = tokens + (size_t)gw * 10;
    const int* t1 = tokens + (size_t)(gw + K1_WAVES) * 10;
#pragma unroll
    for (int l = 0; l < 10; ++l) tokA[l] = t0[l];
#pragma unroll
    for (int l = 0; l < 10; ++l) tokB[l] = t1[l];
  }
#pragma unroll
  for (int l = 0; l < 10; ++l) tA[l] = T1[tokA[l] * 640 + l * 64 + lane];
#pragma unroll
  for (int l = 0; l < 10; ++l) tB[l] = T1[tokB[l] * 640 + l * 64 + lane];
  {  // tokens for items 2,3
    const int* t2 = tokens + (size_t)(gw + 2 * K1_WAVES) * 10;
    const int* t3 = tokens + (size_t)(gw + 3 * K1_WAVES) * 10;
#pragma unroll
    for (int l = 0; l < 10; ++l) tokA[l] = t2[l];
#pragma unroll
    for (int l = 0; l < 10; ++l) tokB[l] = t3[l];
  }

#pragma unroll 1
  for (int it = 0; it < K1_ITEMS; it += 2) {
    int item = gw + it * K1_WAVES;
    K1_STEP(item, tA, tokA, gw + (it + 4) * K1_WAVES);
    K1_STEP(item + K1_WAVES, tB, tokB, gw + (it + 5) * K1_WAVES);
  }
}

// ---------------- K2: per-tree: child_ff(h160) -> heads + s + M partials ----------------
__global__ __launch_bounds__(256) void k_stage2(const float* __restrict__ hbuf,
    const float* __restrict__ W1, const float* __restrict__ b1v,
    const float* __restrict__ W2, const float* __restrict__ b2v,
    const float* __restrict__ fmW, const float* __restrict__ fmb,
    const float* __restrict__ tsW, const float* __restrict__ tsb,
    const float* __restrict__ suW, const float* __restrict__ sub_b,
    float* __restrict__ out, float* __restrict__ partials) {
  __shared__ float h1b_lds[32 * 68];
  __shared__ float code_lds[32 * 20];
  __shared__ float ff_lds[32 * 12];
  int tid = threadIdx.x;
  int lane = tid & 63;
  int wid = __builtin_amdgcn_readfirstlane(tid >> 6);
  int treeBase = blockIdx.x * 32;
  {   // GEMM: wave computes 8 trees, lane = output o
    int tw = treeBase + wid * 8;
    float acc[8];
#pragma unroll
    for (int t = 0; t < 8; ++t) acc[t] = b1v[lane];
    const float* wrow = W1 + lane * 160;
    const float* xbase = hbuf + (size_t)tw * 160;
    for (int k = 0; k < 160; k += 4) {
      float4 wv = *(const float4*)(wrow + k);
#pragma unroll
      for (int t = 0; t < 8; ++t) {
        float4 xv = *(const float4*)(xbase + t * 160 + k);  // wave-uniform -> s_load
        acc[t] = fmaf(wv.x, xv.x, acc[t]);
        acc[t] = fmaf(wv.y, xv.y, acc[t]);
        acc[t] = fmaf(wv.z, xv.z, acc[t]);
        acc[t] = fmaf(wv.w, xv.w, acc[t]);
      }
    }
#pragma unroll
    for (int t = 0; t < 8; ++t)
      h1b_lds[(wid * 8 + t) * 68 + lane] = fmaxf(acc[t], 0.f);
  }
  __syncthreads();
  {   // code = W2 @ relu(h1b) + b2 : thread -> (tree t2, outputs jj, jj+8)
    int t2 = tid >> 3, jj = tid & 7;
    float c0 = b2v[jj], c1 = b2v[jj + 8];
    const float* w2a = W2 + jj * 64;
    const float* w2b = W2 + (jj + 8) * 64;
    const float* hb = &h1b_lds[t2 * 68];
    for (int o = 0; o < 64; o += 4) {
      float4 hv = *(const float4*)(hb + o);
      float4 a4 = *(const float4*)(w2a + o);
      float4 b4 = *(const float4*)(w2b + o);
      c0 = fmaf(a4.x, hv.x, c0); c0 = fmaf(a4.y, hv.y, c0);
      c0 = fmaf(a4.z, hv.z, c0); c0 = fmaf(a4.w, hv.w, c0);
      c1 = fmaf(b4.x, hv.x, c1); c1 = fmaf(b4.y, hv.y, c1);
      c1 = fmaf(b4.z, hv.z, c1); c1 = fmaf(b4.w, hv.w, c1);
    }
    code_lds[t2 * 20 + jj] = c0;
    code_lds[t2 * 20 + jj + 8] = c1;
  }
  __syncthreads();
  {   // ff_out = fmW @ code + fmb
    int t = tid >> 3, q = tid & 7;
    float f = fmb[q];
    const float* cw = fmW + q * 16;
    const float* cl = &code_lds[t * 20];
#pragma unroll
    for (int j4 = 0; j4 < 16; j4 += 4) {
      float4 cv = *(const float4*)(cl + j4);
      float4 wv = *(const float4*)(cw + j4);
      f = fmaf(wv.x, cv.x, f); f = fmaf(wv.y, cv.y, f);
      f = fmaf(wv.z, cv.z, f); f = fmaf(wv.w, cv.w, f);
    }
    ff_lds[t * 12 + q] = f;
  }
  __syncthreads();
  {   // s (unnormalized) to d_out; score for tid<32
    int t = tid >> 3, r = tid & 7;
    float4 f0 = *(const float4*)&ff_lds[t * 12];
    float4 f1 = *(const float4*)&ff_lds[t * 12 + 4];
    int tree = treeBase + t;
    float* od = out + (size_t)BB + (size_t)tree * 128 + r * 16;
#pragma unroll
    for (int cc = 0; cc < 16; ++cc) {
      int c = r * 16 + cc;
      const float* u = suW + c * 8;
      float4 u0 = *(const float4*)(u);
      float4 u1 = *(const float4*)(u + 4);
      float sv = sub_b[c];
      sv = fmaf(u0.x, f0.x, sv); sv = fmaf(u0.y, f0.y, sv);
      sv = fmaf(u0.z, f0.z, sv); sv = fmaf(u0.w, f0.w, sv);
      sv = fmaf(u1.x, f1.x, sv); sv = fmaf(u1.y, f1.y, sv);
      sv = fmaf(u1.z, f1.z, sv); sv = fmaf(u1.w, f1.w, sv);
      od[cc] = sv;
    }
    if (tid < 32) {
      int tt = tid;
      float4 g0 = *(const float4*)&ff_lds[tt * 12];
      float4 g1 = *(const float4*)&ff_lds[tt * 12 + 4];
      float sc = tsb[0];
      sc = fmaf(tsW[0], g0.x, sc); sc = fmaf(tsW[1], g0.y, sc);
      sc = fmaf(tsW[2], g0.z, sc); sc = fmaf(tsW[3], g0.w, sc);
      sc = fmaf(tsW[4], g1.x, sc); sc = fmaf(tsW[5], g1.y, sc);
      sc = fmaf(tsW[6], g1.z, sc); sc = fmaf(tsW[7], g1.w, sc);
      out[treeBase + tt] = tanhf(sc);
    }
  }
  {   // per-wave 9x9 second-moment partials over its 8 trees (f9 = [ff_out, 1])
    int waveId = blockIdx.x * 4 + wid;
    float* pw = partials + (size_t)waveId * 88;
#pragma unroll
    for (int rep = 0; rep < 2; ++rep) {
      int e = lane + rep * 64;
      if (e < 81) {
        int i = e / 9, jx = e - i * 9;
        float m = 0.f;
#pragma unroll
        for (int t = 0; t < 8; ++t) {
          const float* fr = &ff_lds[(wid * 8 + t) * 12];
          float fi = (i  < 8) ? fr[i]  : 1.f;
          float fj = (jx < 8) ? fr[jx] : 1.f;
          m = fmaf(fi, fj, m);
        }
        pw[e] = m;
      }
    }
  }
}

// ---------------- K3a: reduce M partials (4096 waves) in f64 ----------------
__global__ __launch_bounds__(256) void k_reduce(const float* __restrict__ partials,
                                                double* __restrict__ Msum) {
  __shared__ double red[256];
  int e = blockIdx.x;    // 0..80
  double s = 0.0;
  for (int w = threadIdx.x; w < 4096; w += 256)
    s += (double)partials[(size_t)w * 88 + e];
  red[threadIdx.x] = s;
  __syncthreads();
  for (int off = 128; off > 0; off >>= 1) {
    if (threadIdx.x < off) red[threadIdx.x] += red[threadIdx.x + off];
    __syncthreads();
  }
  if (threadIdx.x == 0) Msum[e] = red[0];
}

// ---------------- K3b: per-column BN stats -> A[c], B[c] ----------------
__global__ __launch_bounds__(128) void k_stats(const double* __restrict__ Msum,
    const float* __restrict__ suW, const float* __restrict__ sub_b,
    const float* __restrict__ gamma, const float* __restrict__ beta,
    float* __restrict__ statsA, float* __restrict__ statsB) {
  int c = threadIdx.x;
  double u[9];
#pragma unroll
  for (int q = 0; q < 8; ++q) u[q] = (double)suW[c * 8 + q];
  u[8] = (double)sub_b[c];
  double S1 = 0.0;
#pragma unroll
  for (int i = 0; i < 9; ++i) S1 += u[i] * Msum[72 + i];   // row 8 of M = sums of f9
  double mu = S1 / (double)BB;
  double E2 = 0.0;
#pragma unroll
  for (int i = 0; i < 9; ++i) {
    double acc = 0.0;
#pragma unroll
    for (int jx = 0; jx < 9; ++jx) acc += u[jx] * Msum[i * 9 + jx];
    E2 += u[i] * acc;
  }
  E2 /= (double)BB;
  double var = E2 - mu * mu;
  if (var < 0.0) var = 0.0;
  double rs = 1.0 / sqrt(var + (double)EPSBN);
  double A = (double)gamma[c] * rs;
  statsA[c] = (float)A;
  statsB[c] = (float)((double)beta[c] - mu * A);
}

// ---------------- K4: in-place normalize summary region of d_out ----------------
__global__ __launch_bounds__(256) void k_norm(float* __restrict__ out,
    const float* __restrict__ statsA, const float* __restrict__ statsB) {
  int idx = blockIdx.x * 256 + threadIdx.x;   // 1,048,576 float4s
  float4* p = (float4*)(out + BB);
  float4 v = p[idx];
  int c4 = idx & 31;
  float4 a = ((const float4*)statsA)[c4];
  float4 b = ((const float4*)statsB)[c4];
  v.x = fmaf(v.x, a.x, b.x);
  v.y = fmaf(v.y, a.y, b.y);
  v.z = fmaf(v.z, a.z, b.z);
  v.w = fmaf(v.w, a.w, b.w);
  p[idx] = v;
}

extern "C" void kernel_launch(void* const* d_in, const int* in_sizes, int n_in,
                              void* d_out, int out_size, void* d_ws, size_t ws_size,
                              hipStream_t stream) {
  const int*   tokens = (const int*)d_in[0];
  const float* emb   = (const float*)d_in[1];
  const float* w_ih  = (const float*)d_in[2];
  const float* b_ih  = (const float*)d_in[3];
  const float* b_hh  = (const float*)d_in[4];
  const float* ffW1  = (const float*)d_in[5];
  const float* ffb1  = (const float*)d_in[6];
  const float* ffW2  = (const float*)d_in[7];
  const float* ffb2  = (const float*)d_in[8];
  const float* fmW   = (const float*)d_in[9];
  const float* fmb   = (const float*)d_in[10];
  const float* tsW   = (const float*)d_in[11];
  const float* tsb   = (const float*)d_in[12];
  const float* suW   = (const float*)d_in[13];
  const float* sub_b = (const float*)d_in[14];
  const float* gamma = (const float*)d_in[15];
  const float* beta  = (const float*)d_in[16];
  float* out = (float*)d_out;
  float* ws = (float*)d_ws;

  float*  T1       = ws;                               // 1,280,000 f
  float*  hbuf     = T1 + 1280000;                     // 5,242,880 f
  float*  partials = hbuf + 5242880;                   // 360,448 f
  double* Msum     = (double*)(partials + 360448);     // 81 d (8B aligned)
  float*  statsA   = (float*)(Msum + 82);              // 128 f (16B aligned)
  float*  statsB   = statsA + 128;                     // 128 f
  float*  W3       = statsB + 128;                     // 4096 f
  float*  bias3    = W3 + 4096;                        // 64 f

  hipLaunchKernelGGL(k_table,  dim3(5000), dim3(256), 0, stream, emb, ffW1, T1);
  hipLaunchKernelGGL(k_fuse,   dim3(17),   dim3(256), 0, stream,
                     w_ih, b_ih, b_hh, ffW2, ffb2, W3, bias3);
  hipLaunchKernelGGL(k_stage1, dim3(4096), dim3(256), 0, stream,
                     tokens, T1, ffb1, W3, bias3, hbuf);
  hipLaunchKernelGGL(k_stage2, dim3(1024), dim3(256), 0, stream,
                     hbuf, ffW1, ffb1, ffW2, ffb2, fmW, fmb, tsW, tsb, suW, sub_b,
                     out, partials);
  hipLaunchKernelGGL(k_reduce, dim3(81),   dim3(256), 0, stream, partials, Msum);
  hipLaunchKernelGGL(k_stats,  dim3(1),    dim3(128), 0, stream,
                     Msum, suW, sub_b, gamma, beta, statsA, statsB);
  hipLaunchKernelGGL(k_norm,   dim3(4096), dim3(256), 0, stream, out, statsA, statsB);
}